// Round 4
// baseline (1235.209 us; speedup 1.0000x reference)
//
#include <hip/hip_runtime.h>
#include <hip/hip_bf16.h>
#include <cstdint>
#include <cmath>

// Problem dims (Transformer-XL)
#define QL      512
#define BS      4
#define DMODEL  1024
#define NL      4
#define NH      16
#define DHEAD   64
#define DINNER  4096
#define MLEN    512
#define KLEN_   1024   // MLEN + QL
#define HD_     1024   // NH*DHEAD
#define THD     3072   // 3*HD
#define ROWS_H   2048  // QL*BS

typedef __attribute__((ext_vector_type(8))) __bf16 bf16x8;
typedef __attribute__((ext_vector_type(4))) __bf16 bf16x4;
typedef __attribute__((ext_vector_type(4))) float  f32x4;

enum EpiMode { EPI_F32 = 0, EPI_BF16 = 1, EPI_RELU_BF16 = 2 };

// softmax in exp2 units: scale = (1/sqrt(DH)) * log2(e)
#define SCL 0.18033688011112042f

// async global->LDS, 16B per lane; LDS dest = wave-uniform base + lane*16
__device__ __forceinline__ void glds16(const void* g, void* l) {
  __builtin_amdgcn_global_load_lds(
      (const __attribute__((address_space(1))) unsigned int*)g,
      (__attribute__((address_space(3))) unsigned int*)l, 16, 0, 0);
}

// ======================= MFMA GEMM: C = A(MxK) * Bt(NxK)^T =======================
// m97 structure: global_load_lds width-16 staging into linear LDS [row][64B] (BK=32).
// Source pre-swizzle kq = (l&3)^((l>>2)&3) + read-side quad XOR: 8-way -> 4-way bank conflict.
// blockIdx.z: batch OR split-K chunk via element strides sA (A k-offset), Bn, Cn.
template<int BM, int BN, int WMT, int WNT, int EPI>
__global__ __launch_bounds__(256) void gemm_bt(
    const __bf16* __restrict__ A, const __bf16* __restrict__ Bt,
    void* __restrict__ Cv, const float* __restrict__ bias,
    int K, int lda, int ldb, int ldc,
    long sA, long Bn, long Cn)
{
  constexpr int WCOLS = BN / (WNT * 16);
  constexpr int WROWS = BM / (WMT * 16);
  static_assert(WCOLS * WROWS == 4, "must be 4 waves");
  __shared__ __align__(16) char smem[(BM + BN) * 64];
  char* sAm = smem;            // [BM][64B]  (32 bf16 of k per row, quad-swizzled)
  char* sBm = smem + BM * 64;  // [BN][64B]

  const int bz = blockIdx.z;
  A  += (size_t)bz * sA;
  Bt += (size_t)bz * Bn;
  const size_t coff = (size_t)bz * Cn;

  const int tid  = threadIdx.x;
  const int wave = tid >> 6, lane = tid & 63;
  const int quad = lane >> 4, mrow = lane & 15;
  const int wr = wave / WCOLS, wc = wave % WCOLS;
  const int bm0 = blockIdx.x * BM, bn0 = blockIdx.y * BN;

  // staging source coords: chunk = 16 rows x 64B; lane l -> row l>>2, k-quad swizzled
  const int srow = lane >> 2;
  const int skq  = (lane & 3) ^ (srow & 3);
  const __bf16* gA = A  + (size_t)(bm0 + wave * (BM / 64) * 16 + srow) * lda + skq * 8;
  const __bf16* gB = Bt + (size_t)(bn0 + wave * (BN / 64) * 16 + srow) * ldb + skq * 8;
  char* lA = sAm + wave * (BM / 64) * 1024;
  char* lB = sBm + wave * (BN / 64) * 1024;

  const int aswz = (quad ^ (mrow & 3)) << 4;   // read-side swizzle (row&3 == mrow&3)

  const f32x4 zero = {0.f, 0.f, 0.f, 0.f};
  f32x4 acc[WMT][WNT];
#pragma unroll
  for (int a = 0; a < WMT; ++a)
#pragma unroll
    for (int b = 0; b < WNT; ++b) acc[a][b] = zero;

  for (int k0 = 0; k0 < K; k0 += 32) {
#pragma unroll
    for (int p = 0; p < BM / 64; ++p)
      glds16(gA + (size_t)p * 16 * lda + k0, lA + p * 1024);
#pragma unroll
    for (int p = 0; p < BN / 64; ++p)
      glds16(gB + (size_t)p * 16 * ldb + k0, lB + p * 1024);
    __syncthreads();   // compiler drains vmcnt before barrier -> tiles complete
    bf16x8 afr[WMT], bfr[WNT];
#pragma unroll
    for (int mt = 0; mt < WMT; ++mt)
      afr[mt] = *(const bf16x8*)(sAm + (wr * (WMT * 16) + mt * 16 + mrow) * 64 + aswz);
#pragma unroll
    for (int nt = 0; nt < WNT; ++nt)
      bfr[nt] = *(const bf16x8*)(sBm + (wc * (WNT * 16) + nt * 16 + mrow) * 64 + aswz);
#pragma unroll
    for (int mt = 0; mt < WMT; ++mt)
#pragma unroll
      for (int nt = 0; nt < WNT; ++nt)
        acc[mt][nt] = __builtin_amdgcn_mfma_f32_16x16x32_bf16(afr[mt], bfr[nt], acc[mt][nt], 0, 0, 0);
    __syncthreads();
  }

#pragma unroll
  for (int mt = 0; mt < WMT; ++mt) {
#pragma unroll
    for (int nt = 0; nt < WNT; ++nt) {
#pragma unroll
      for (int rr = 0; rr < 4; ++rr) {
        int gm = bm0 + wr * (WMT * 16) + mt * 16 + quad * 4 + rr;
        int gn = bn0 + wc * (WNT * 16) + nt * 16 + mrow;
        float val = acc[mt][nt][rr];
        if constexpr (EPI == EPI_F32) {
          ((float*)Cv)[coff + (size_t)gm * ldc + gn] = val;
        } else if constexpr (EPI == EPI_BF16) {
          ((__bf16*)Cv)[coff + (size_t)gm * ldc + gn] = (__bf16)val;
        } else { // EPI_RELU_BF16
          val += bias[gn];
          ((__bf16*)Cv)[coff + (size_t)gm * ldc + gn] = (__bf16)fmaxf(val, 0.f);
        }
      }
    }
  }
}

// ======================= fused flash attention with rel-shift, j-split x2 =======================
// 1024 blocks: (bn, t, z) decoded XCD-aware (bn's 16 blocks share one XCD's L2); longest
// blocks (t=7) dispatched first to tighten the tail. T14 async-stage: V(k) issued before
// BAR1 (hidden under raw/AC MFMA); K(k+1), rk(k+2) issued after BAR2 (hidden under
// softmax+PV). Softmax runs in exp2 units (SCL = 0.125*log2e). Partials: normalized bf16
// o/l + fp32 (m,l) in log2 units; combined exactly by attn_combine.
__global__ __launch_bounds__(256) void flash_attn(
    const __bf16* __restrict__ qu,   // [bn][QL][64]
    const __bf16* __restrict__ qv,   // [bn][QL][64]
    const __bf16* __restrict__ heads,// [(j*BS+b)*THD + HD_ + n*64 + d] (K part)
    const __bf16* __restrict__ rk,   // [c][n*64+d], ld = HD_
    const __bf16* __restrict__ vt,   // [bn][64][KLEN_]  (V^T)
    __bf16* __restrict__ avp,        // [z][bn][512][64] bf16, normalized o/l
    float* __restrict__ mlpart)      // [z][bn][512][2]  f32 (m, l) in exp2 units
{
  __shared__ __align__(16) char kh_t[64 * 144];   // K tile [j][d]; later P tile [i][j]
  __shared__ __align__(16) char rv_t[64 * 144];   // rk chunk [c][d]; later V^T tile [d][j]
  __shared__ float raw[64 * 132];                 // raw[i_local][ring 128 cols], pad to 132

  const int wgid = blockIdx.x;          // 0..1023
  const int xcd  = wgid & 7;
  const int slotw = wgid >> 3;          // 0..127
  const int bn   = ((slotw >> 4) << 3) + xcd;   // 0..63
  const int inner = slotw & 15;
  const int t    = 7 - (inner & 7);     // i-tile 0..7, longest (t=7) first
  const int z    = inner >> 3;          // j-half 0..1
  const int i0   = t * 64;
  const int b    = bn >> 4, n = bn & 15;
  const int nt   = t + 9;
  const int h    = (nt + 1) >> 1;
  const int ks   = z ? h : 0;
  const int ke   = z ? nt : h;

  const int tid = threadIdx.x;
  const int wave = tid >> 6, lane = tid & 63;
  const int quad = lane >> 4, mrow = lane & 15;
  const f32x4 zero = {0.f, 0.f, 0.f, 0.f};

  const __bf16* qub = qu + (size_t)bn * QL * DHEAD;
  const __bf16* qvb = qv + (size_t)bn * QL * DHEAD;
  const int qrow = i0 + wave * 16 + mrow;
  bf16x8 quf0 = *(const bf16x8*)(qub + (size_t)qrow * 64 + quad * 8);
  bf16x8 quf1 = *(const bf16x8*)(qub + (size_t)qrow * 64 + 32 + quad * 8);
  bf16x8 qvf0 = *(const bf16x8*)(qvb + (size_t)qrow * 64 + quad * 8);
  bf16x8 qvf1 = *(const bf16x8*)(qvb + (size_t)qrow * 64 + 32 + quad * 8);

  f32x4 o[4];
#pragma unroll
  for (int dt = 0; dt < 4; ++dt) o[dt] = zero;
  float m_r[4], l_r[4];
#pragma unroll
  for (int rr = 0; rr < 4; ++rr) { m_r[rr] = -3.0e38f; l_r[rr] = 0.f; }

  const int sr = tid >> 3;          // 0..31
  const int sc = (tid & 7) * 8;     // 0..56

  const __bf16* vtb = vt + (size_t)bn * (DHEAD * KLEN_);

  // ---- pre-loop: stage + raw-MFMA chunk(ks); prefetch K(ks), rk chunk(ks+1) ----
  const int c0 = 448 - i0;
  const int cpre = c0 + 64 * ks;
#pragma unroll
  for (int p = 0; p < 2; ++p) {
    int r = p * 32 + sr;
    bf16x8 vv = *(const bf16x8*)(rk + (size_t)(cpre + r) * HD_ + n * 64 + sc);
    *(bf16x8*)(rv_t + r * 144 + sc * 2) = vv;
  }
  __syncthreads();
  {
    int slotc = ((cpre >> 6) & 1) * 64;
    __builtin_amdgcn_s_setprio(1);
#pragma unroll
    for (int ct = 0; ct < 4; ++ct) {
      bf16x8 b0 = *(const bf16x8*)(rv_t + (ct * 16 + mrow) * 144 + quad * 16);
      bf16x8 b1 = *(const bf16x8*)(rv_t + (ct * 16 + mrow) * 144 + 64 + quad * 16);
      f32x4 r = __builtin_amdgcn_mfma_f32_16x16x32_bf16(qvf0, b0, zero, 0, 0, 0);
      r = __builtin_amdgcn_mfma_f32_16x16x32_bf16(qvf1, b1, r, 0, 0, 0);
#pragma unroll
      for (int rr = 0; rr < 4; ++rr)
        raw[(wave * 16 + quad * 4 + rr) * 132 + slotc + ct * 16 + mrow] = r[rr];
    }
    __builtin_amdgcn_s_setprio(0);
  }
  // prefetch for first loop iter (global -> regs; waits handled by compiler at use)
  bf16x8 kreg0, kreg1, rreg0, rreg1, vreg0, vreg1;
  {
    int j0 = ks * 64;
    kreg0 = *(const bf16x8*)(heads + (size_t)((j0 + sr) * BS + b) * THD + HD_ + n * 64 + sc);
    kreg1 = *(const bf16x8*)(heads + (size_t)((j0 + 32 + sr) * BS + b) * THD + HD_ + n * 64 + sc);
    int c1 = c0 + 64 * (ks + 1);
    if (c1 < KLEN_) {
      rreg0 = *(const bf16x8*)(rk + (size_t)(c1 + sr) * HD_ + n * 64 + sc);
      rreg1 = *(const bf16x8*)(rk + (size_t)(c1 + 32 + sr) * HD_ + n * 64 + sc);
    }
  }
  __syncthreads();   // raw visible; rv_t reads done

  const int i_base = i0 + wave * 16 + quad * 4;
  for (int k = ks; k < ke; ++k) {
    const int j0 = k * 64;
    const int cw = c0 + 64 * (k + 1);
    // (A) issue V(k) loads (consumed after BAR2, hidden under MFMA phase);
    //     commit prefetched K (and rk chunk) to LDS
    vreg0 = *(const bf16x8*)(vtb + (size_t)sr * KLEN_ + j0 + sc);
    vreg1 = *(const bf16x8*)(vtb + (size_t)(32 + sr) * KLEN_ + j0 + sc);
    *(bf16x8*)(kh_t + sr * 144 + sc * 2) = kreg0;
    *(bf16x8*)(kh_t + (32 + sr) * 144 + sc * 2) = kreg1;
    if (cw < KLEN_) {
      *(bf16x8*)(rv_t + sr * 144 + sc * 2) = rreg0;
      *(bf16x8*)(rv_t + (32 + sr) * 144 + sc * 2) = rreg1;
    }
    __syncthreads();   // BAR1: tiles staged
    // (C) raw MFMA for chunk(k+1) + AC MFMA
    __builtin_amdgcn_s_setprio(1);
    if (cw < KLEN_) {
      int slotc = ((cw >> 6) & 1) * 64;
#pragma unroll
      for (int ct = 0; ct < 4; ++ct) {
        bf16x8 b0 = *(const bf16x8*)(rv_t + (ct * 16 + mrow) * 144 + quad * 16);
        bf16x8 b1 = *(const bf16x8*)(rv_t + (ct * 16 + mrow) * 144 + 64 + quad * 16);
        f32x4 r = __builtin_amdgcn_mfma_f32_16x16x32_bf16(qvf0, b0, zero, 0, 0, 0);
        r = __builtin_amdgcn_mfma_f32_16x16x32_bf16(qvf1, b1, r, 0, 0, 0);
#pragma unroll
        for (int rr = 0; rr < 4; ++rr)
          raw[(wave * 16 + quad * 4 + rr) * 132 + slotc + ct * 16 + mrow] = r[rr];
      }
    }
    f32x4 s[4];
#pragma unroll
    for (int ct = 0; ct < 4; ++ct) {
      bf16x8 b0 = *(const bf16x8*)(kh_t + (ct * 16 + mrow) * 144 + quad * 16);
      bf16x8 b1 = *(const bf16x8*)(kh_t + (ct * 16 + mrow) * 144 + 64 + quad * 16);
      s[ct] = __builtin_amdgcn_mfma_f32_16x16x32_bf16(quf0, b0, zero, 0, 0, 0);
      s[ct] = __builtin_amdgcn_mfma_f32_16x16x32_bf16(quf1, b1, s[ct], 0, 0, 0);
    }
    __builtin_amdgcn_s_setprio(0);
    __syncthreads();   // BAR2: kh_t(K)/rv_t(rk) reads done; raw visible
    // (E) issue next-iter K / rk prefetches (hidden under softmax+PV), commit V
    if (k + 1 < ke) {
      int j1 = (k + 1) * 64;
      kreg0 = *(const bf16x8*)(heads + (size_t)((j1 + sr) * BS + b) * THD + HD_ + n * 64 + sc);
      kreg1 = *(const bf16x8*)(heads + (size_t)((j1 + 32 + sr) * BS + b) * THD + HD_ + n * 64 + sc);
      int cn2 = c0 + 64 * (k + 2);
      if (cn2 < KLEN_) {
        rreg0 = *(const bf16x8*)(rk + (size_t)(cn2 + sr) * HD_ + n * 64 + sc);
        rreg1 = *(const bf16x8*)(rk + (size_t)(cn2 + 32 + sr) * HD_ + n * 64 + sc);
      }
    }
    *(bf16x8*)(rv_t + sr * 144 + sc * 2) = vreg0;
    *(bf16x8*)(rv_t + (32 + sr) * 144 + sc * 2) = vreg1;
    // rel-shift add + mask + online softmax (exp2 units)
#pragma unroll
    for (int ct = 0; ct < 4; ++ct) {
#pragma unroll
      for (int rr = 0; rr < 4; ++rr) {
        int i = i_base + rr;
        int j = j0 + ct * 16 + mrow;
        float val;
        if (j - i <= MLEN) {
          int c = j - i + (QL - 1);
          int col = ((c >> 6) & 1) * 64 + (c & 63);
          val = (s[ct][rr] + raw[(wave * 16 + quad * 4 + rr) * 132 + col]) * SCL;
        } else val = -3.0e38f;
        s[ct][rr] = val;
      }
    }
    float alpha[4];
#pragma unroll
    for (int rr = 0; rr < 4; ++rr) {
      float mx = fmaxf(fmaxf(s[0][rr], s[1][rr]), fmaxf(s[2][rr], s[3][rr]));
#pragma unroll
      for (int off = 1; off < 16; off <<= 1) mx = fmaxf(mx, __shfl_xor(mx, off));
      float m_new = fmaxf(m_r[rr], mx);
      alpha[rr] = exp2f(m_r[rr] - m_new);
      m_r[rr] = m_new;
      float rs = 0.f;
#pragma unroll
      for (int ct = 0; ct < 4; ++ct) {
        float pv = exp2f(s[ct][rr] - m_new);
        s[ct][rr] = pv;
        rs += pv;
      }
#pragma unroll
      for (int off = 1; off < 16; off <<= 1) rs += __shfl_xor(rs, off);
      l_r[rr] = l_r[rr] * alpha[rr] + rs;
    }
#pragma unroll
    for (int dt = 0; dt < 4; ++dt)
#pragma unroll
      for (int rr = 0; rr < 4; ++rr) o[dt][rr] *= alpha[rr];
    // write P (bf16) into kh_t (K tile dead since BAR2)
#pragma unroll
    for (int ct = 0; ct < 4; ++ct)
#pragma unroll
      for (int rr = 0; rr < 4; ++rr)
        ((__bf16*)kh_t)[(wave * 16 + quad * 4 + rr) * 72 + ct * 16 + mrow] = (__bf16)s[ct][rr];
    __syncthreads();   // BAR3: V^T staged + P visible
    // (H) PV MFMA
    {
      bf16x8 pf0 = *(const bf16x8*)(kh_t + (wave * 16 + mrow) * 144 + quad * 16);
      bf16x8 pf1 = *(const bf16x8*)(kh_t + (wave * 16 + mrow) * 144 + 64 + quad * 16);
      __builtin_amdgcn_s_setprio(1);
#pragma unroll
      for (int dt = 0; dt < 4; ++dt) {
        bf16x8 vf0 = *(const bf16x8*)(rv_t + (dt * 16 + mrow) * 144 + quad * 16);
        bf16x8 vf1 = *(const bf16x8*)(rv_t + (dt * 16 + mrow) * 144 + 64 + quad * 16);
        o[dt] = __builtin_amdgcn_mfma_f32_16x16x32_bf16(pf0, vf0, o[dt], 0, 0, 0);
        o[dt] = __builtin_amdgcn_mfma_f32_16x16x32_bf16(pf1, vf1, o[dt], 0, 0, 0);
      }
      __builtin_amdgcn_s_setprio(0);
    }
    __syncthreads();   // BAR4: before next-iter staging overwrites tiles
  }

  // epilogue: write normalized bf16 partial (o/l) + fp32 (m,l)
  const size_t prow = ((size_t)z * 64 + bn) * 512;
#pragma unroll
  for (int rr = 0; rr < 4; ++rr) {
    int i = i_base + rr;
    float inv = 1.0f / l_r[rr];
#pragma unroll
    for (int dt = 0; dt < 4; ++dt)
      avp[(prow + i) * 64 + dt * 16 + mrow] = (__bf16)(o[dt][rr] * inv);
  }
  if (mrow == 0) {
#pragma unroll
    for (int rr = 0; rr < 4; ++rr) {
      int i = i_base + rr;
      mlpart[(prow + i) * 2]     = m_r[rr];
      mlpart[(prow + i) * 2 + 1] = l_r[rr];
    }
  }
}

// combine the two j-half partials -> av bf16 (exact given partials; m in exp2 units)
__global__ __launch_bounds__(256) void attn_combine(
    const __bf16* __restrict__ avp, const float* __restrict__ mlpart,
    __bf16* __restrict__ av)
{
  int idx = blockIdx.x * 256 + threadIdx.x;   // 64*512*16 total
  int dq = idx & 15;
  int i  = (idx >> 4) & 511;
  int bn = idx >> 13;
  int b = bn >> 4, n = bn & 15;
  size_t r0 = (size_t)bn * 512 + i;
  size_t r1 = r0 + (size_t)64 * 512;
  float m1 = mlpart[r0 * 2], l1 = mlpart[r0 * 2 + 1];
  float m2 = mlpart[r1 * 2], l2 = mlpart[r1 * 2 + 1];
  float m  = fmaxf(m1, m2);
  float w1 = l1 * exp2f(m1 - m), w2 = l2 * exp2f(m2 - m);
  float inv = 1.0f / (w1 + w2);
  w1 *= inv; w2 *= inv;
  bf16x4 o1 = *(const bf16x4*)(avp + r0 * 64 + dq * 4);
  bf16x4 o2 = *(const bf16x4*)(avp + r1 * 64 + dq * 4);
  bf16x4 ov;
#pragma unroll
  for (int j = 0; j < 4; ++j)
    ov[j] = (__bf16)((float)o1[j] * w1 + (float)o2[j] * w2);
  *(bf16x4*)(av + ((size_t)i * BS + b) * HD_ + n * 64 + dq * 4) = ov;
}

// ======================= helpers =======================

__global__ __launch_bounds__(256) void transpose_f32_bf16(
    const float* __restrict__ in, unsigned short* __restrict__ out, int R, int C)
{
  __shared__ float tile[64][66];
  int c0 = blockIdx.x * 64, r0 = blockIdx.y * 64;
  int tx = threadIdx.x, ty = threadIdx.y;  // (32,8)
#pragma unroll
  for (int s = 0; s < 8; ++s) {
    int r = ty + s * 8;
    const float* p = in + (size_t)(r0 + r) * C + c0 + 2 * tx;
    tile[r][2 * tx]     = p[0];
    tile[r][2 * tx + 1] = p[1];
  }
  __syncthreads();
#pragma unroll
  for (int s = 0; s < 8; ++s) {
    int c = ty + s * 8;
    __bf16 lo = (__bf16)tile[2 * tx][c];
    __bf16 hi = (__bf16)tile[2 * tx + 1][c];
    unsigned int w = (unsigned int)*(unsigned short*)&lo |
                     ((unsigned int)*(unsigned short*)&hi << 16);
    *(unsigned int*)(out + (size_t)(c0 + c) * R + r0 + 2 * tx) = w;
  }
}

__global__ __launch_bounds__(256) void cast_f32_bf16(const float* __restrict__ in,
                                                     __bf16* __restrict__ out, int n)
{
  int i = blockIdx.x * 256 + threadIdx.x;
  if (i < n) out[i] = (__bf16)in[i];
}

__global__ __launch_bounds__(256) void posemb_kernel(__bf16* __restrict__ r)
{
  int idx = blockIdx.x * 256 + threadIdx.x;        // KLEN_*DMODEL total
  int p = idx >> 10, c = idx & 1023;
  int t = c & 511;
  float invf = __expf(-((float)t / 512.0f) * 9.210340371976184f); // 10000^(-2t/D)
  float ang = (float)(KLEN_ - 1 - p) * invf;
  float val = (c < 512) ? sinf(ang) : cosf(ang);
  r[idx] = (__bf16)val;
}

__global__ __launch_bounds__(256) void init_h(const float* __restrict__ x,
                                              float* __restrict__ hm,
                                              __bf16* __restrict__ hbf, int n)
{
  int i = blockIdx.x * 256 + threadIdx.x;
  if (i < n) { float t = x[i]; hm[i] = t; hbf[i] = (__bf16)t; }
}

__global__ __launch_bounds__(256) void build_quqv(const __bf16* __restrict__ heads,
                                                  const float* __restrict__ u,
                                                  const float* __restrict__ v,
                                                  __bf16* __restrict__ qu,
                                                  __bf16* __restrict__ qv)
{
  int idx = blockIdx.x * 256 + threadIdx.x;   // BS*NH*QL*DHEAD total
  int d = idx & 63;
  int i = (idx >> 6) & (QL - 1);
  int bn = idx >> 15;
  int b = bn >> 4, n = bn & 15;
  float q = (float)heads[(size_t)((MLEN + i) * BS + b) * THD + n * 64 + d];
  int ud = n * 64 + d;
  qu[idx] = (__bf16)(q + u[ud]);
  qv[idx] = (__bf16)(q + v[ud]);
}

__global__ __launch_bounds__(256) void build_vt(const unsigned short* __restrict__ heads,
                                                unsigned short* __restrict__ vt)
{
  __shared__ unsigned short tile[64][65];
  int bn = blockIdx.y; int b = bn >> 4, n = bn & 15;
  int j0 = blockIdx.x * 64;
  int tx = threadIdx.x, ty = threadIdx.y;  // (64,4)
#pragma unroll
  for (int s = 0; s < 16; ++s) {
    int j = ty + s * 4;
    tile[j][tx] = heads[(size_t)((j0 + j) * BS + b) * THD + 2048 + n * 64 + tx];
  }
  __syncthreads();
#pragma unroll
  for (int s = 0; s < 16; ++s) {
    int d = ty + s * 4;
    vt[(size_t)bn * DHEAD * KLEN_ + (size_t)d * KLEN_ + j0 + tx] = tile[tx][d];
  }
}

// residual LN; t = hm + d0 (+ d1) (+ bias); writes hm, hbf (and optionally outf)
__global__ __launch_bounds__(256) void ln_kernel(float* __restrict__ hm,
                                                 const float* __restrict__ d0,
                                                 const float* __restrict__ d1,
                                                 const float* __restrict__ bias,
                                                 const float* __restrict__ g,
                                                 const float* __restrict__ b,
                                                 __bf16* __restrict__ hbf,
                                                 float* __restrict__ outf)
{
  int row = blockIdx.x;
  size_t base = (size_t)row * DMODEL;
  int tid = threadIdx.x;
  float x[4]; float sum = 0.f, sq = 0.f;
#pragma unroll
  for (int p = 0; p < 4; ++p) {
    int c = p * 256 + tid;
    float t = hm[base + c] + d0[base + c];
    if (d1) t += d1[base + c];
    if (bias) t += bias[c];
    x[p] = t; sum += t; sq += t * t;
  }
#pragma unroll
  for (int off = 32; off > 0; off >>= 1) { sum += __shfl_xor(sum, off); sq += __shfl_xor(sq, off); }
  __shared__ float rs[4], rq[4];
  int wave = tid >> 6, lane = tid & 63;
  if (lane == 0) { rs[wave] = sum; rq[wave] = sq; }
  __syncthreads();
  sum = rs[0] + rs[1] + rs[2] + rs[3];
  sq  = rq[0] + rq[1] + rq[2] + rq[3];
  float mu  = sum * (1.0f / DMODEL);
  float var = sq * (1.0f / DMODEL) - mu * mu;
  float rstd = rsqrtf(var + 1e-5f);
#pragma unroll
  for (int p = 0; p < 4; ++p) {
    int c = p * 256 + tid;
    float y = (x[p] - mu) * rstd * g[c] + b[c];
    hm[base + c] = y;
    hbf[base + c] = (__bf16)y;
    if (outf) outf[base + c] = y;
  }
}

// ======================= host =======================
extern "C" void kernel_launch(void* const* d_in, const int* in_sizes, int n_in,
                              void* d_out, int out_size, void* d_ws, size_t ws_size,
                              hipStream_t stream) {
  (void)in_sizes; (void)n_in; (void)out_size; (void)ws_size;
  const float* x    = (const float*)d_in[0];
  const float* mems = (const float*)d_in[1];
  const float* u    = (const float*)d_in[2];
  const float* v    = (const float*)d_in[3];
  const float* Wqkv = (const float*)d_in[4];
  const float* Wo   = (const float*)d_in[5];
  const float* Wr   = (const float*)d_in[6];
  const float* ln1g = (const float*)d_in[7];
  const float* ln1b = (const float*)d_in[8];
  const float* W1   = (const float*)d_in[9];
  const float* b1   = (const float*)d_in[10];
  const float* W2   = (const float*)d_in[11];
  const float* b2   = (const float*)d_in[12];
  const float* ln2g = (const float*)d_in[13];
  const float* ln2b = (const float*)d_in[14];

  // ---- workspace carve-up (~78 MB total, identical to last passing run) ----
  size_t off = 0;
  char* ws = (char*)d_ws;
  auto alloc = [&](size_t bytes) { size_t o = off; off += (bytes + 255) & ~(size_t)255; return o; };
  __bf16* wT    = (__bf16*)(ws + alloc((size_t)DINNER * DMODEL * 2));        // 8.4 MB (W_r^T upfront; per-GEMM W^T; flash avp)
  char*   R1    = (char*)(ws + alloc((size_t)(2 * ROWS_H) * THD * 2));       // 25.2 MB: heads | proj+ff1
  __bf16* heads = (__bf16*)R1;
  float*  proj  = (float*)R1;                                                // 8.4 MB (after heads dead)
  __bf16* ff1   = (__bf16*)(R1 + (size_t)ROWS_H * DMODEL * 4);               // 16.8 MB
  __bf16* catb  = (__bf16*)(ws + alloc((size_t)(2 * ROWS_H) * DMODEL * 2));  // 8.4 MB: [memsb | hbf] contiguous
  __bf16* memsb = catb;                                                      // rows 0..2047 (mems, cast)
  __bf16* hbf   = catb + (size_t)ROWS_H * DMODEL;                            // rows 2048..4095 (h, bf16)
  __bf16* av    = catb;                   // alias: memsb dead between QKV-gemm and next-layer cast
  float*  mlprt = (float*)hbf;            // alias: hbf dead between QKV-gemm and ln1 (1 MB used)
  __bf16* avp   = wT;                     // alias: wT dead between QKV-gemm and Wo transpose (8.4 MB)
  __bf16* r_bf  = (__bf16*)(ws + alloc((size_t)KLEN_ * DMODEL * 2));         // 2 MB
  __bf16* rk4   = (__bf16*)(ws + alloc((size_t)NL * KLEN_ * HD_ * 2));       // 8.4 MB: all layers upfront
  __bf16* qu    = (__bf16*)(ws + alloc((size_t)2 * BS * NH * QL * DHEAD * 2));// 8.4 MB: qu|qv contiguous
  __bf16* qv    = qu + (size_t)BS * NH * QL * DHEAD;
  float*  ff2p  = (float*)qu;             // FF2 split-K partial (qu/qv dead by then)
  __bf16* vt    = (__bf16*)(ws + alloc((size_t)BS * NH * DHEAD * KLEN_ * 2));// 8.4 MB
  float*  hm    = (float*)(ws + alloc((size_t)ROWS_H * DMODEL * 4));         // 8.4 MB

  posemb_kernel<<<(KLEN_ * DMODEL) / 256, 256, 0, stream>>>(r_bf);
  init_h<<<(ROWS_H * DMODEL) / 256, 256, 0, stream>>>(x, hm, hbf, ROWS_H * DMODEL);

  // ---- rk for ALL layers upfront, batched over blockIdx.z ----
  for (int i = 0; i < NL; ++i)
    transpose_f32_bf16<<<dim3(HD_ / 64, DMODEL / 64), dim3(32, 8), 0, stream>>>(
        Wr + (size_t)i * DMODEL * HD_, (unsigned short*)(wT + (size_t)i * HD_ * DMODEL),
        DMODEL, HD_);
  gemm_bt<128, 128, 4, 4, EPI_BF16><<<dim3(8, 8, NL), 256, 0, stream>>>(
      r_bf, wT, rk4, nullptr, DMODEL, DMODEL, DMODEL, HD_,
      0, (long)HD_ * DMODEL, (long)KLEN_ * HD_);

  for (int i = 0; i < NL; ++i) {
    // ---- QKV: one M=4096 GEMM over [memsb | hbf] (768 blocks) ----
    cast_f32_bf16<<<(MLEN * BS * DMODEL) / 256, 256, 0, stream>>>(
        mems + (size_t)i * MLEN * BS * DMODEL, memsb, MLEN * BS * DMODEL);
    transpose_f32_bf16<<<dim3(THD / 64, DMODEL / 64), dim3(32, 8), 0, stream>>>(
        Wqkv + (size_t)i * DMODEL * THD, (unsigned short*)wT, DMODEL, THD);
    gemm_bt<128, 128, 4, 4, EPI_BF16><<<dim3(32, 24, 1), 256, 0, stream>>>(
        catb, wT, heads, nullptr, DMODEL, DMODEL, DMODEL, THD, 0, 0, 0);

    build_quqv<<<(BS * NH * QL * DHEAD) / 256, 256, 0, stream>>>(heads, u, v, qu, qv);
    build_vt<<<dim3(KLEN_ / 64, BS * NH), dim3(64, 4), 0, stream>>>(
        (const unsigned short*)heads, (unsigned short*)vt);

    // ---- fused attention: j-split x2, 1024 blocks, then exact combine ----
    flash_attn<<<dim3(1024), 256, 0, stream>>>(
        qu, qv, heads, rk4 + (size_t)i * KLEN_ * HD_, vt, avp, mlprt);
    attn_combine<<<(64 * 512 * 16) / 256, 256, 0, stream>>>(avp, mlprt, av);

    // ---- O-proj: BN=64 -> 256 blocks ----
    transpose_f32_bf16<<<dim3(DMODEL / 64, HD_ / 64), dim3(32, 8), 0, stream>>>(
        Wo + (size_t)i * HD_ * DMODEL, (unsigned short*)wT, HD_, DMODEL);
    gemm_bt<128, 64, 4, 2, EPI_F32><<<dim3(16, 16, 1), 256, 0, stream>>>(
        av, wT, proj, nullptr, HD_, HD_, HD_, DMODEL, 0, 0, 0);
    ln_kernel<<<ROWS_H, 256, 0, stream>>>(hm, proj, nullptr, nullptr,
                                          ln1g + i * DMODEL, ln1b + i * DMODEL, hbf, nullptr);

    // ---- FF1 (512 blocks) ----
    transpose_f32_bf16<<<dim3(DINNER / 64, DMODEL / 64), dim3(32, 8), 0, stream>>>(
        W1 + (size_t)i * DMODEL * DINNER, (unsigned short*)wT, DMODEL, DINNER);
    gemm_bt<128, 128, 4, 4, EPI_RELU_BF16><<<dim3(16, 32, 1), 256, 0, stream>>>(
        hbf, wT, ff1, b1 + i * DINNER, DMODEL, DMODEL, DMODEL, DINNER, 0, 0, 0);

    // ---- FF2: split-K=2 x BN=64 -> 512 blocks; bias folded into ln ----
    transpose_f32_bf16<<<dim3(DMODEL / 64, DINNER / 64), dim3(32, 8), 0, stream>>>(
        W2 + (size_t)i * DINNER * DMODEL, (unsigned short*)wT, DINNER, DMODEL);
    gemm_bt<128, 64, 4, 2, EPI_F32><<<dim3(16, 16, 2), 256, 0, stream>>>(
        ff1, wT, proj, nullptr, DINNER / 2, DINNER, DINNER, DMODEL,
        (long)(DINNER / 2), (long)(DINNER / 2), (long)(ff2p - proj));
    ln_kernel<<<ROWS_H, 256, 0, stream>>>(hm, proj, ff2p, b2 + i * DMODEL,
                                          ln2g + i * DMODEL, ln2b + i * DMODEL, hbf,
                                          (i == NL - 1) ? (float*)d_out : nullptr);
  }
}

// Round 5
// 1132.321 us; speedup vs baseline: 1.0909x; 1.0909x over previous
//
#include <hip/hip_runtime.h>
#include <hip/hip_bf16.h>
#include <cstdint>
#include <cmath>

// Problem dims (Transformer-XL)
#define QL      512
#define BS      4
#define DMODEL  1024
#define NL      4
#define NH      16
#define DHEAD   64
#define DINNER  4096
#define MLEN    512
#define KLEN_   1024   // MLEN + QL
#define HD_     1024   // NH*DHEAD
#define THD     3072   // 3*HD
#define ROWS_H   2048  // QL*BS

typedef __attribute__((ext_vector_type(8))) __bf16 bf16x8;
typedef __attribute__((ext_vector_type(4))) __bf16 bf16x4;
typedef __attribute__((ext_vector_type(4))) float  f32x4;

enum EpiMode { EPI_F32 = 0, EPI_BF16 = 1, EPI_RELU_BF16 = 2 };

// softmax in exp2 units: scale = (1/sqrt(DH)) * log2(e)
#define SCL 0.18033688011112042f

// async global->LDS, 16B per lane; LDS dest = wave-uniform base + lane*16
__device__ __forceinline__ void glds16(const void* g, void* l) {
  __builtin_amdgcn_global_load_lds(
      (const __attribute__((address_space(1))) unsigned int*)g,
      (__attribute__((address_space(3))) unsigned int*)l, 16, 0, 0);
}

// ======================= MFMA GEMM: C = A(MxK) * Bt(NxK)^T =======================
// m97 structure + BK=64: two 64B k-planes per operand staged via global_load_lds
// (linear lane->LDS mapping preserved per-plane), 32 MFMA per barrier span ->
// half the barrier drains of BK=32. Source pre-swizzle kq=(l&3)^((l>>2)&3) +
// read-side quad XOR: 4-way bank conflict on ds_read_b128.
// blockIdx.z: batch OR split-K chunk via element strides sA (A k-offset), Bn, Cn.
template<int BM, int BN, int WMT, int WNT, int EPI>
__global__ __launch_bounds__(256) void gemm_bt(
    const __bf16* __restrict__ A, const __bf16* __restrict__ Bt,
    void* __restrict__ Cv, const float* __restrict__ bias,
    int K, int lda, int ldb, int ldc,
    long sA, long Bn, long Cn)
{
  constexpr int WCOLS = BN / (WNT * 16);
  constexpr int WROWS = BM / (WMT * 16);
  static_assert(WCOLS * WROWS == 4, "must be 4 waves");
  __shared__ __align__(16) char smem[(BM + BN) * 128];
  char* sA0 = smem;                       // [BM][64B] k-plane 0
  char* sA1 = smem + BM * 64;             // [BM][64B] k-plane 1
  char* sB0 = smem + BM * 128;            // [BN][64B] k-plane 0
  char* sB1 = smem + BM * 128 + BN * 64;  // [BN][64B] k-plane 1

  const int bz = blockIdx.z;
  A  += (size_t)bz * sA;
  Bt += (size_t)bz * Bn;
  const size_t coff = (size_t)bz * Cn;

  const int tid  = threadIdx.x;
  const int wave = tid >> 6, lane = tid & 63;
  const int quad = lane >> 4, mrow = lane & 15;
  const int wr = wave / WCOLS, wc = wave % WCOLS;
  const int bm0 = blockIdx.x * BM, bn0 = blockIdx.y * BN;

  // staging source coords: chunk = 16 rows x 64B; lane l -> row l>>2, k-quad swizzled
  const int srow = lane >> 2;
  const int skq  = (lane & 3) ^ (srow & 3);
  const __bf16* gA = A  + (size_t)(bm0 + wave * (BM / 64) * 16 + srow) * lda + skq * 8;
  const __bf16* gB = Bt + (size_t)(bn0 + wave * (BN / 64) * 16 + srow) * ldb + skq * 8;
  char* lA0 = sA0 + wave * (BM / 64) * 1024;
  char* lA1 = sA1 + wave * (BM / 64) * 1024;
  char* lB0 = sB0 + wave * (BN / 64) * 1024;
  char* lB1 = sB1 + wave * (BN / 64) * 1024;

  const int aswz = (quad ^ (mrow & 3)) << 4;   // read-side swizzle (row&3 == mrow&3)

  const f32x4 zero = {0.f, 0.f, 0.f, 0.f};
  f32x4 acc[WMT][WNT];
#pragma unroll
  for (int a = 0; a < WMT; ++a)
#pragma unroll
    for (int b = 0; b < WNT; ++b) acc[a][b] = zero;

  for (int k0 = 0; k0 < K; k0 += 64) {
#pragma unroll
    for (int p = 0; p < BM / 64; ++p) {
      glds16(gA + (size_t)p * 16 * lda + k0,      lA0 + p * 1024);
      glds16(gA + (size_t)p * 16 * lda + k0 + 32, lA1 + p * 1024);
    }
#pragma unroll
    for (int p = 0; p < BN / 64; ++p) {
      glds16(gB + (size_t)p * 16 * ldb + k0,      lB0 + p * 1024);
      glds16(gB + (size_t)p * 16 * ldb + k0 + 32, lB1 + p * 1024);
    }
    __syncthreads();   // compiler drains vmcnt before barrier -> tiles complete
    bf16x8 afr[WMT], bfr[WNT];
    // k-plane 0
#pragma unroll
    for (int mt = 0; mt < WMT; ++mt)
      afr[mt] = *(const bf16x8*)(sA0 + (wr * (WMT * 16) + mt * 16 + mrow) * 64 + aswz);
#pragma unroll
    for (int nt = 0; nt < WNT; ++nt)
      bfr[nt] = *(const bf16x8*)(sB0 + (wc * (WNT * 16) + nt * 16 + mrow) * 64 + aswz);
#pragma unroll
    for (int mt = 0; mt < WMT; ++mt)
#pragma unroll
      for (int nt = 0; nt < WNT; ++nt)
        acc[mt][nt] = __builtin_amdgcn_mfma_f32_16x16x32_bf16(afr[mt], bfr[nt], acc[mt][nt], 0, 0, 0);
    // k-plane 1
#pragma unroll
    for (int mt = 0; mt < WMT; ++mt)
      afr[mt] = *(const bf16x8*)(sA1 + (wr * (WMT * 16) + mt * 16 + mrow) * 64 + aswz);
#pragma unroll
    for (int nt = 0; nt < WNT; ++nt)
      bfr[nt] = *(const bf16x8*)(sB1 + (wc * (WNT * 16) + nt * 16 + mrow) * 64 + aswz);
#pragma unroll
    for (int mt = 0; mt < WMT; ++mt)
#pragma unroll
      for (int nt = 0; nt < WNT; ++nt)
        acc[mt][nt] = __builtin_amdgcn_mfma_f32_16x16x32_bf16(afr[mt], bfr[nt], acc[mt][nt], 0, 0, 0);
    __syncthreads();
  }

#pragma unroll
  for (int mt = 0; mt < WMT; ++mt) {
#pragma unroll
    for (int nt = 0; nt < WNT; ++nt) {
#pragma unroll
      for (int rr = 0; rr < 4; ++rr) {
        int gm = bm0 + wr * (WMT * 16) + mt * 16 + quad * 4 + rr;
        int gn = bn0 + wc * (WNT * 16) + nt * 16 + mrow;
        float val = acc[mt][nt][rr];
        if constexpr (EPI == EPI_F32) {
          ((float*)Cv)[coff + (size_t)gm * ldc + gn] = val;
        } else if constexpr (EPI == EPI_BF16) {
          ((__bf16*)Cv)[coff + (size_t)gm * ldc + gn] = (__bf16)val;
        } else { // EPI_RELU_BF16
          val += bias[gn];
          ((__bf16*)Cv)[coff + (size_t)gm * ldc + gn] = (__bf16)fmaxf(val, 0.f);
        }
      }
    }
  }
}

// ======================= fused flash attention with rel-shift, j-split x2 =======================
// 1024 blocks: (bn, t, z) decoded XCD-aware (bn's 16 blocks share one XCD's L2).
// raw ring stored BF16 -> LDS 35.6 KB -> 4 blocks/CU -> entire grid resident at once;
// barrier/softmax stalls of one block hide under the other 3 co-resident blocks.
// T14 async-stage kept: V(k) issued pre-BAR1, K(k+1)/rk(k+2) issued post-BAR2.
// Softmax in exp2 units. Partials: normalized bf16 o/l + fp32 (m,l); exact combine.
__global__ __launch_bounds__(256) void flash_attn(
    const __bf16* __restrict__ qu,   // [bn][QL][64]
    const __bf16* __restrict__ qv,   // [bn][QL][64]
    const __bf16* __restrict__ heads,// [(j*BS+b)*THD + HD_ + n*64 + d] (K part)
    const __bf16* __restrict__ rk,   // [c][n*64+d], ld = HD_
    const __bf16* __restrict__ vt,   // [bn][64][KLEN_]  (V^T)
    __bf16* __restrict__ avp,        // [z][bn][512][64] bf16, normalized o/l
    float* __restrict__ mlpart)      // [z][bn][512][2]  f32 (m, l) in exp2 units
{
  __shared__ __align__(16) char kh_t[64 * 144];   // K tile [j][d]; later P tile [i][j]
  __shared__ __align__(16) char rv_t[64 * 144];   // rk chunk [c][d]; later V^T tile [d][j]
  __shared__ __align__(4) __bf16 rawb[64 * 134];  // raw[i_local][ring 128 cols] bf16, pad 134

  const int wgid = blockIdx.x;          // 0..1023
  const int xcd  = wgid & 7;
  const int slotw = wgid >> 3;          // 0..127
  const int bn   = ((slotw >> 4) << 3) + xcd;   // 0..63
  const int inner = slotw & 15;
  const int t    = 7 - (inner & 7);     // i-tile 0..7, longest (t=7) first
  const int z    = inner >> 3;          // j-half 0..1
  const int i0   = t * 64;
  const int b    = bn >> 4, n = bn & 15;
  const int nt   = t + 9;
  const int h    = (nt + 1) >> 1;
  const int ks   = z ? h : 0;
  const int ke   = z ? nt : h;

  const int tid = threadIdx.x;
  const int wave = tid >> 6, lane = tid & 63;
  const int quad = lane >> 4, mrow = lane & 15;
  const f32x4 zero = {0.f, 0.f, 0.f, 0.f};

  const __bf16* qub = qu + (size_t)bn * QL * DHEAD;
  const __bf16* qvb = qv + (size_t)bn * QL * DHEAD;
  const int qrow = i0 + wave * 16 + mrow;
  bf16x8 quf0 = *(const bf16x8*)(qub + (size_t)qrow * 64 + quad * 8);
  bf16x8 quf1 = *(const bf16x8*)(qub + (size_t)qrow * 64 + 32 + quad * 8);
  bf16x8 qvf0 = *(const bf16x8*)(qvb + (size_t)qrow * 64 + quad * 8);
  bf16x8 qvf1 = *(const bf16x8*)(qvb + (size_t)qrow * 64 + 32 + quad * 8);

  f32x4 o[4];
#pragma unroll
  for (int dt = 0; dt < 4; ++dt) o[dt] = zero;
  float m_r[4], l_r[4];
#pragma unroll
  for (int rr = 0; rr < 4; ++rr) { m_r[rr] = -3.0e38f; l_r[rr] = 0.f; }

  const int sr = tid >> 3;          // 0..31
  const int sc = (tid & 7) * 8;     // 0..56

  const __bf16* vtb = vt + (size_t)bn * (DHEAD * KLEN_);

  // ---- pre-loop: stage + raw-MFMA chunk(ks); prefetch K(ks), rk chunk(ks+1) ----
  const int c0 = 448 - i0;
  const int cpre = c0 + 64 * ks;
#pragma unroll
  for (int p = 0; p < 2; ++p) {
    int r = p * 32 + sr;
    bf16x8 vv = *(const bf16x8*)(rk + (size_t)(cpre + r) * HD_ + n * 64 + sc);
    *(bf16x8*)(rv_t + r * 144 + sc * 2) = vv;
  }
  __syncthreads();
  {
    int slotc = ((cpre >> 6) & 1) * 64;
    __builtin_amdgcn_s_setprio(1);
#pragma unroll
    for (int ct = 0; ct < 4; ++ct) {
      bf16x8 b0 = *(const bf16x8*)(rv_t + (ct * 16 + mrow) * 144 + quad * 16);
      bf16x8 b1 = *(const bf16x8*)(rv_t + (ct * 16 + mrow) * 144 + 64 + quad * 16);
      f32x4 r = __builtin_amdgcn_mfma_f32_16x16x32_bf16(qvf0, b0, zero, 0, 0, 0);
      r = __builtin_amdgcn_mfma_f32_16x16x32_bf16(qvf1, b1, r, 0, 0, 0);
#pragma unroll
      for (int rr = 0; rr < 4; ++rr)
        rawb[(wave * 16 + quad * 4 + rr) * 134 + slotc + ct * 16 + mrow] = (__bf16)r[rr];
    }
    __builtin_amdgcn_s_setprio(0);
  }
  // prefetch for first loop iter (global -> regs; waits handled by compiler at use)
  bf16x8 kreg0, kreg1, rreg0, rreg1, vreg0, vreg1;
  {
    int j0 = ks * 64;
    kreg0 = *(const bf16x8*)(heads + (size_t)((j0 + sr) * BS + b) * THD + HD_ + n * 64 + sc);
    kreg1 = *(const bf16x8*)(heads + (size_t)((j0 + 32 + sr) * BS + b) * THD + HD_ + n * 64 + sc);
    int c1 = c0 + 64 * (ks + 1);
    if (c1 < KLEN_) {
      rreg0 = *(const bf16x8*)(rk + (size_t)(c1 + sr) * HD_ + n * 64 + sc);
      rreg1 = *(const bf16x8*)(rk + (size_t)(c1 + 32 + sr) * HD_ + n * 64 + sc);
    }
  }
  __syncthreads();   // raw visible; rv_t reads done

  const int i_base = i0 + wave * 16 + quad * 4;
  for (int k = ks; k < ke; ++k) {
    const int j0 = k * 64;
    const int cw = c0 + 64 * (k + 1);
    // (A) issue V(k) loads (consumed after BAR2, hidden under MFMA phase);
    //     commit prefetched K (and rk chunk) to LDS
    vreg0 = *(const bf16x8*)(vtb + (size_t)sr * KLEN_ + j0 + sc);
    vreg1 = *(const bf16x8*)(vtb + (size_t)(32 + sr) * KLEN_ + j0 + sc);
    *(bf16x8*)(kh_t + sr * 144 + sc * 2) = kreg0;
    *(bf16x8*)(kh_t + (32 + sr) * 144 + sc * 2) = kreg1;
    if (cw < KLEN_) {
      *(bf16x8*)(rv_t + sr * 144 + sc * 2) = rreg0;
      *(bf16x8*)(rv_t + (32 + sr) * 144 + sc * 2) = rreg1;
    }
    __syncthreads();   // BAR1: tiles staged
    // (C) raw MFMA for chunk(k+1) + AC MFMA
    __builtin_amdgcn_s_setprio(1);
    if (cw < KLEN_) {
      int slotc = ((cw >> 6) & 1) * 64;
#pragma unroll
      for (int ct = 0; ct < 4; ++ct) {
        bf16x8 b0 = *(const bf16x8*)(rv_t + (ct * 16 + mrow) * 144 + quad * 16);
        bf16x8 b1 = *(const bf16x8*)(rv_t + (ct * 16 + mrow) * 144 + 64 + quad * 16);
        f32x4 r = __builtin_amdgcn_mfma_f32_16x16x32_bf16(qvf0, b0, zero, 0, 0, 0);
        r = __builtin_amdgcn_mfma_f32_16x16x32_bf16(qvf1, b1, r, 0, 0, 0);
#pragma unroll
        for (int rr = 0; rr < 4; ++rr)
          rawb[(wave * 16 + quad * 4 + rr) * 134 + slotc + ct * 16 + mrow] = (__bf16)r[rr];
      }
    }
    f32x4 s[4];
#pragma unroll
    for (int ct = 0; ct < 4; ++ct) {
      bf16x8 b0 = *(const bf16x8*)(kh_t + (ct * 16 + mrow) * 144 + quad * 16);
      bf16x8 b1 = *(const bf16x8*)(kh_t + (ct * 16 + mrow) * 144 + 64 + quad * 16);
      s[ct] = __builtin_amdgcn_mfma_f32_16x16x32_bf16(quf0, b0, zero, 0, 0, 0);
      s[ct] = __builtin_amdgcn_mfma_f32_16x16x32_bf16(quf1, b1, s[ct], 0, 0, 0);
    }
    __builtin_amdgcn_s_setprio(0);
    __syncthreads();   // BAR2: kh_t(K)/rv_t(rk) reads done; raw visible
    // (E) issue next-iter K / rk prefetches (hidden under softmax+PV), commit V
    if (k + 1 < ke) {
      int j1 = (k + 1) * 64;
      kreg0 = *(const bf16x8*)(heads + (size_t)((j1 + sr) * BS + b) * THD + HD_ + n * 64 + sc);
      kreg1 = *(const bf16x8*)(heads + (size_t)((j1 + 32 + sr) * BS + b) * THD + HD_ + n * 64 + sc);
      int cn2 = c0 + 64 * (k + 2);
      if (cn2 < KLEN_) {
        rreg0 = *(const bf16x8*)(rk + (size_t)(cn2 + sr) * HD_ + n * 64 + sc);
        rreg1 = *(const bf16x8*)(rk + (size_t)(cn2 + 32 + sr) * HD_ + n * 64 + sc);
      }
    }
    *(bf16x8*)(rv_t + sr * 144 + sc * 2) = vreg0;
    *(bf16x8*)(rv_t + (32 + sr) * 144 + sc * 2) = vreg1;
    // rel-shift add + mask + online softmax (exp2 units)
#pragma unroll
    for (int ct = 0; ct < 4; ++ct) {
#pragma unroll
      for (int rr = 0; rr < 4; ++rr) {
        int i = i_base + rr;
        int j = j0 + ct * 16 + mrow;
        float val;
        if (j - i <= MLEN) {
          int c = j - i + (QL - 1);
          int col = ((c >> 6) & 1) * 64 + (c & 63);
          val = (s[ct][rr] + (float)rawb[(wave * 16 + quad * 4 + rr) * 134 + col]) * SCL;
        } else val = -3.0e38f;
        s[ct][rr] = val;
      }
    }
    float alpha[4];
#pragma unroll
    for (int rr = 0; rr < 4; ++rr) {
      float mx = fmaxf(fmaxf(s[0][rr], s[1][rr]), fmaxf(s[2][rr], s[3][rr]));
#pragma unroll
      for (int off = 1; off < 16; off <<= 1) mx = fmaxf(mx, __shfl_xor(mx, off));
      float m_new = fmaxf(m_r[rr], mx);
      alpha[rr] = exp2f(m_r[rr] - m_new);
      m_r[rr] = m_new;
      float rs = 0.f;
#pragma unroll
      for (int ct = 0; ct < 4; ++ct) {
        float pv = exp2f(s[ct][rr] - m_new);
        s[ct][rr] = pv;
        rs += pv;
      }
#pragma unroll
      for (int off = 1; off < 16; off <<= 1) rs += __shfl_xor(rs, off);
      l_r[rr] = l_r[rr] * alpha[rr] + rs;
    }
#pragma unroll
    for (int dt = 0; dt < 4; ++dt)
#pragma unroll
      for (int rr = 0; rr < 4; ++rr) o[dt][rr] *= alpha[rr];
    // write P (bf16) into kh_t (K tile dead since BAR2)
#pragma unroll
    for (int ct = 0; ct < 4; ++ct)
#pragma unroll
      for (int rr = 0; rr < 4; ++rr)
        ((__bf16*)kh_t)[(wave * 16 + quad * 4 + rr) * 72 + ct * 16 + mrow] = (__bf16)s[ct][rr];
    __syncthreads();   // BAR3: V^T staged + P visible
    // (H) PV MFMA
    {
      bf16x8 pf0 = *(const bf16x8*)(kh_t + (wave * 16 + mrow) * 144 + quad * 16);
      bf16x8 pf1 = *(const bf16x8*)(kh_t + (wave * 16 + mrow) * 144 + 64 + quad * 16);
      __builtin_amdgcn_s_setprio(1);
#pragma unroll
      for (int dt = 0; dt < 4; ++dt) {
        bf16x8 vf0 = *(const bf16x8*)(rv_t + (dt * 16 + mrow) * 144 + quad * 16);
        bf16x8 vf1 = *(const bf16x8*)(rv_t + (dt * 16 + mrow) * 144 + 64 + quad * 16);
        o[dt] = __builtin_amdgcn_mfma_f32_16x16x32_bf16(pf0, vf0, o[dt], 0, 0, 0);
        o[dt] = __builtin_amdgcn_mfma_f32_16x16x32_bf16(pf1, vf1, o[dt], 0, 0, 0);
      }
      __builtin_amdgcn_s_setprio(0);
    }
    __syncthreads();   // BAR4: before next-iter staging overwrites tiles
  }

  // epilogue: write normalized bf16 partial (o/l) + fp32 (m,l)
  const size_t prow = ((size_t)z * 64 + bn) * 512;
#pragma unroll
  for (int rr = 0; rr < 4; ++rr) {
    int i = i_base + rr;
    float inv = 1.0f / l_r[rr];
#pragma unroll
    for (int dt = 0; dt < 4; ++dt)
      avp[(prow + i) * 64 + dt * 16 + mrow] = (__bf16)(o[dt][rr] * inv);
  }
  if (mrow == 0) {
#pragma unroll
    for (int rr = 0; rr < 4; ++rr) {
      int i = i_base + rr;
      mlpart[(prow + i) * 2]     = m_r[rr];
      mlpart[(prow + i) * 2 + 1] = l_r[rr];
    }
  }
}

// combine the two j-half partials -> av bf16 (exact given partials; m in exp2 units)
__global__ __launch_bounds__(256) void attn_combine(
    const __bf16* __restrict__ avp, const float* __restrict__ mlpart,
    __bf16* __restrict__ av)
{
  int idx = blockIdx.x * 256 + threadIdx.x;   // 64*512*16 total
  int dq = idx & 15;
  int i  = (idx >> 4) & 511;
  int bn = idx >> 13;
  int b = bn >> 4, n = bn & 15;
  size_t r0 = (size_t)bn * 512 + i;
  size_t r1 = r0 + (size_t)64 * 512;
  float m1 = mlpart[r0 * 2], l1 = mlpart[r0 * 2 + 1];
  float m2 = mlpart[r1 * 2], l2 = mlpart[r1 * 2 + 1];
  float m  = fmaxf(m1, m2);
  float w1 = l1 * exp2f(m1 - m), w2 = l2 * exp2f(m2 - m);
  float inv = 1.0f / (w1 + w2);
  w1 *= inv; w2 *= inv;
  bf16x4 o1 = *(const bf16x4*)(avp + r0 * 64 + dq * 4);
  bf16x4 o2 = *(const bf16x4*)(avp + r1 * 64 + dq * 4);
  bf16x4 ov;
#pragma unroll
  for (int j = 0; j < 4; ++j)
    ov[j] = (__bf16)((float)o1[j] * w1 + (float)o2[j] * w2);
  *(bf16x4*)(av + ((size_t)i * BS + b) * HD_ + n * 64 + dq * 4) = ov;
}

// ======================= helpers =======================

__global__ __launch_bounds__(256) void transpose_f32_bf16(
    const float* __restrict__ in, unsigned short* __restrict__ out, int R, int C)
{
  __shared__ float tile[64][66];
  int c0 = blockIdx.x * 64, r0 = blockIdx.y * 64;
  int tx = threadIdx.x, ty = threadIdx.y;  // (32,8)
#pragma unroll
  for (int s = 0; s < 8; ++s) {
    int r = ty + s * 8;
    const float* p = in + (size_t)(r0 + r) * C + c0 + 2 * tx;
    tile[r][2 * tx]     = p[0];
    tile[r][2 * tx + 1] = p[1];
  }
  __syncthreads();
#pragma unroll
  for (int s = 0; s < 8; ++s) {
    int c = ty + s * 8;
    __bf16 lo = (__bf16)tile[2 * tx][c];
    __bf16 hi = (__bf16)tile[2 * tx + 1][c];
    unsigned int w = (unsigned int)*(unsigned short*)&lo |
                     ((unsigned int)*(unsigned short*)&hi << 16);
    *(unsigned int*)(out + (size_t)(c0 + c) * R + r0 + 2 * tx) = w;
  }
}

__global__ __launch_bounds__(256) void cast_f32_bf16(const float* __restrict__ in,
                                                     __bf16* __restrict__ out, int n)
{
  int i = blockIdx.x * 256 + threadIdx.x;
  if (i < n) out[i] = (__bf16)in[i];
}

__global__ __launch_bounds__(256) void posemb_kernel(__bf16* __restrict__ r)
{
  int idx = blockIdx.x * 256 + threadIdx.x;        // KLEN_*DMODEL total
  int p = idx >> 10, c = idx & 1023;
  int t = c & 511;
  float invf = __expf(-((float)t / 512.0f) * 9.210340371976184f); // 10000^(-2t/D)
  float ang = (float)(KLEN_ - 1 - p) * invf;
  float val = (c < 512) ? sinf(ang) : cosf(ang);
  r[idx] = (__bf16)val;
}

__global__ __launch_bounds__(256) void init_h(const float* __restrict__ x,
                                              float* __restrict__ hm,
                                              __bf16* __restrict__ hbf, int n)
{
  int i = blockIdx.x * 256 + threadIdx.x;
  if (i < n) { float t = x[i]; hm[i] = t; hbf[i] = (__bf16)t; }
}

__global__ __launch_bounds__(256) void build_quqv(const __bf16* __restrict__ heads,
                                                  const float* __restrict__ u,
                                                  const float* __restrict__ v,
                                                  __bf16* __restrict__ qu,
                                                  __bf16* __restrict__ qv)
{
  int idx = blockIdx.x * 256 + threadIdx.x;   // BS*NH*QL*DHEAD total
  int d = idx & 63;
  int i = (idx >> 6) & (QL - 1);
  int bn = idx >> 15;
  int b = bn >> 4, n = bn & 15;
  float q = (float)heads[(size_t)((MLEN + i) * BS + b) * THD + n * 64 + d];
  int ud = n * 64 + d;
  qu[idx] = (__bf16)(q + u[ud]);
  qv[idx] = (__bf16)(q + v[ud]);
}

__global__ __launch_bounds__(256) void build_vt(const unsigned short* __restrict__ heads,
                                                unsigned short* __restrict__ vt)
{
  __shared__ unsigned short tile[64][65];
  int bn = blockIdx.y; int b = bn >> 4, n = bn & 15;
  int j0 = blockIdx.x * 64;
  int tx = threadIdx.x, ty = threadIdx.y;  // (64,4)
#pragma unroll
  for (int s = 0; s < 16; ++s) {
    int j = ty + s * 4;
    tile[j][tx] = heads[(size_t)((j0 + j) * BS + b) * THD + 2048 + n * 64 + tx];
  }
  __syncthreads();
#pragma unroll
  for (int s = 0; s < 16; ++s) {
    int d = ty + s * 4;
    vt[(size_t)bn * DHEAD * KLEN_ + (size_t)d * KLEN_ + j0 + tx] = tile[tx][d];
  }
}

// residual LN; t = hm + d0 (+ d1) (+ bias); writes hm, hbf (and optionally outf)
__global__ __launch_bounds__(256) void ln_kernel(float* __restrict__ hm,
                                                 const float* __restrict__ d0,
                                                 const float* __restrict__ d1,
                                                 const float* __restrict__ bias,
                                                 const float* __restrict__ g,
                                                 const float* __restrict__ b,
                                                 __bf16* __restrict__ hbf,
                                                 float* __restrict__ outf)
{
  int row = blockIdx.x;
  size_t base = (size_t)row * DMODEL;
  int tid = threadIdx.x;
  float x[4]; float sum = 0.f, sq = 0.f;
#pragma unroll
  for (int p = 0; p < 4; ++p) {
    int c = p * 256 + tid;
    float t = hm[base + c] + d0[base + c];
    if (d1) t += d1[base + c];
    if (bias) t += bias[c];
    x[p] = t; sum += t; sq += t * t;
  }
#pragma unroll
  for (int off = 32; off > 0; off >>= 1) { sum += __shfl_xor(sum, off); sq += __shfl_xor(sq, off); }
  __shared__ float rs[4], rq[4];
  int wave = tid >> 6, lane = tid & 63;
  if (lane == 0) { rs[wave] = sum; rq[wave] = sq; }
  __syncthreads();
  sum = rs[0] + rs[1] + rs[2] + rs[3];
  sq  = rq[0] + rq[1] + rq[2] + rq[3];
  float mu  = sum * (1.0f / DMODEL);
  float var = sq * (1.0f / DMODEL) - mu * mu;
  float rstd = rsqrtf(var + 1e-5f);
#pragma unroll
  for (int p = 0; p < 4; ++p) {
    int c = p * 256 + tid;
    float y = (x[p] - mu) * rstd * g[c] + b[c];
    hm[base + c] = y;
    hbf[base + c] = (__bf16)y;
    if (outf) outf[base + c] = y;
  }
}

// ======================= host =======================
extern "C" void kernel_launch(void* const* d_in, const int* in_sizes, int n_in,
                              void* d_out, int out_size, void* d_ws, size_t ws_size,
                              hipStream_t stream) {
  (void)in_sizes; (void)n_in; (void)out_size; (void)ws_size;
  const float* x    = (const float*)d_in[0];
  const float* mems = (const float*)d_in[1];
  const float* u    = (const float*)d_in[2];
  const float* v    = (const float*)d_in[3];
  const float* Wqkv = (const float*)d_in[4];
  const float* Wo   = (const float*)d_in[5];
  const float* Wr   = (const float*)d_in[6];
  const float* ln1g = (const float*)d_in[7];
  const float* ln1b = (const float*)d_in[8];
  const float* W1   = (const float*)d_in[9];
  const float* b1   = (const float*)d_in[10];
  const float* W2   = (const float*)d_in[11];
  const float* b2   = (const float*)d_in[12];
  const float* ln2g = (const float*)d_in[13];
  const float* ln2b = (const float*)d_in[14];

  // ---- workspace carve-up (~78 MB total, identical to last passing run) ----
  size_t off = 0;
  char* ws = (char*)d_ws;
  auto alloc = [&](size_t bytes) { size_t o = off; off += (bytes + 255) & ~(size_t)255; return o; };
  __bf16* wT    = (__bf16*)(ws + alloc((size_t)DINNER * DMODEL * 2));        // 8.4 MB (W_r^T upfront; per-GEMM W^T; flash avp)
  char*   R1    = (char*)(ws + alloc((size_t)(2 * ROWS_H) * THD * 2));       // 25.2 MB: heads | proj+ff1
  __bf16* heads = (__bf16*)R1;
  float*  proj  = (float*)R1;                                                // 8.4 MB (after heads dead)
  __bf16* ff1   = (__bf16*)(R1 + (size_t)ROWS_H * DMODEL * 4);               // 16.8 MB
  __bf16* catb  = (__bf16*)(ws + alloc((size_t)(2 * ROWS_H) * DMODEL * 2));  // 8.4 MB: [memsb | hbf] contiguous
  __bf16* memsb = catb;                                                      // rows 0..2047 (mems, cast)
  __bf16* hbf   = catb + (size_t)ROWS_H * DMODEL;                            // rows 2048..4095 (h, bf16)
  __bf16* av    = catb;                   // alias: memsb dead between QKV-gemm and next-layer cast
  float*  mlprt = (float*)hbf;            // alias: hbf dead between QKV-gemm and ln1 (1 MB used)
  __bf16* avp   = wT;                     // alias: wT dead between QKV-gemm and Wo transpose (8.4 MB)
  __bf16* r_bf  = (__bf16*)(ws + alloc((size_t)KLEN_ * DMODEL * 2));         // 2 MB
  __bf16* rk4   = (__bf16*)(ws + alloc((size_t)NL * KLEN_ * HD_ * 2));       // 8.4 MB: all layers upfront
  __bf16* qu    = (__bf16*)(ws + alloc((size_t)2 * BS * NH * QL * DHEAD * 2));// 8.4 MB: qu|qv contiguous
  __bf16* qv    = qu + (size_t)BS * NH * QL * DHEAD;
  float*  ff2p  = (float*)qu;             // FF2 split-K partial (qu/qv dead by then)
  __bf16* vt    = (__bf16*)(ws + alloc((size_t)BS * NH * DHEAD * KLEN_ * 2));// 8.4 MB
  float*  hm    = (float*)(ws + alloc((size_t)ROWS_H * DMODEL * 4));         // 8.4 MB

  posemb_kernel<<<(KLEN_ * DMODEL) / 256, 256, 0, stream>>>(r_bf);
  init_h<<<(ROWS_H * DMODEL) / 256, 256, 0, stream>>>(x, hm, hbf, ROWS_H * DMODEL);

  // ---- rk for ALL layers upfront, batched over blockIdx.z ----
  for (int i = 0; i < NL; ++i)
    transpose_f32_bf16<<<dim3(HD_ / 64, DMODEL / 64), dim3(32, 8), 0, stream>>>(
        Wr + (size_t)i * DMODEL * HD_, (unsigned short*)(wT + (size_t)i * HD_ * DMODEL),
        DMODEL, HD_);
  gemm_bt<128, 128, 4, 4, EPI_BF16><<<dim3(8, 8, NL), 256, 0, stream>>>(
      r_bf, wT, rk4, nullptr, DMODEL, DMODEL, DMODEL, HD_,
      0, (long)HD_ * DMODEL, (long)KLEN_ * HD_);

  for (int i = 0; i < NL; ++i) {
    // ---- QKV: one M=4096 GEMM over [memsb | hbf] (768 blocks) ----
    cast_f32_bf16<<<(MLEN * BS * DMODEL) / 256, 256, 0, stream>>>(
        mems + (size_t)i * MLEN * BS * DMODEL, memsb, MLEN * BS * DMODEL);
    transpose_f32_bf16<<<dim3(THD / 64, DMODEL / 64), dim3(32, 8), 0, stream>>>(
        Wqkv + (size_t)i * DMODEL * THD, (unsigned short*)wT, DMODEL, THD);
    gemm_bt<128, 128, 4, 4, EPI_BF16><<<dim3(32, 24, 1), 256, 0, stream>>>(
        catb, wT, heads, nullptr, DMODEL, DMODEL, DMODEL, THD, 0, 0, 0);

    build_quqv<<<(BS * NH * QL * DHEAD) / 256, 256, 0, stream>>>(heads, u, v, qu, qv);
    build_vt<<<dim3(KLEN_ / 64, BS * NH), dim3(64, 4), 0, stream>>>(
        (const unsigned short*)heads, (unsigned short*)vt);

    // ---- fused attention: j-split x2, 1024 blocks (all resident), exact combine ----
    flash_attn<<<dim3(1024), 256, 0, stream>>>(
        qu, qv, heads, rk4 + (size_t)i * KLEN_ * HD_, vt, avp, mlprt);
    attn_combine<<<(64 * 512 * 16) / 256, 256, 0, stream>>>(avp, mlprt, av);

    // ---- O-proj: BN=64 -> 256 blocks ----
    transpose_f32_bf16<<<dim3(DMODEL / 64, HD_ / 64), dim3(32, 8), 0, stream>>>(
        Wo + (size_t)i * HD_ * DMODEL, (unsigned short*)wT, HD_, DMODEL);
    gemm_bt<128, 64, 4, 2, EPI_F32><<<dim3(16, 16, 1), 256, 0, stream>>>(
        av, wT, proj, nullptr, HD_, HD_, HD_, DMODEL, 0, 0, 0);
    ln_kernel<<<ROWS_H, 256, 0, stream>>>(hm, proj, nullptr, nullptr,
                                          ln1g + i * DMODEL, ln1b + i * DMODEL, hbf, nullptr);

    // ---- FF1 (512 blocks) ----
    transpose_f32_bf16<<<dim3(DINNER / 64, DMODEL / 64), dim3(32, 8), 0, stream>>>(
        W1 + (size_t)i * DMODEL * DINNER, (unsigned short*)wT, DMODEL, DINNER);
    gemm_bt<128, 128, 4, 4, EPI_RELU_BF16><<<dim3(16, 32, 1), 256, 0, stream>>>(
        hbf, wT, ff1, b1 + i * DINNER, DMODEL, DMODEL, DMODEL, DINNER, 0, 0, 0);

    // ---- FF2: split-K=2 x BN=64 -> 512 blocks; bias folded into ln ----
    transpose_f32_bf16<<<dim3(DMODEL / 64, DINNER / 64), dim3(32, 8), 0, stream>>>(
        W2 + (size_t)i * DINNER * DMODEL, (unsigned short*)wT, DINNER, DMODEL);
    gemm_bt<128, 64, 4, 2, EPI_F32><<<dim3(16, 16, 2), 256, 0, stream>>>(
        ff1, wT, proj, nullptr, DINNER / 2, DINNER, DINNER, DMODEL,
        (long)(DINNER / 2), (long)(DINNER / 2), (long)(ff2p - proj));
    ln_kernel<<<ROWS_H, 256, 0, stream>>>(hm, proj, ff2p, b2 + i * DMODEL,
                                          ln2g + i * DMODEL, ln2b + i * DMODEL, hbf,
                                          (i == NL - 1) ? (float*)d_out : nullptr);
  }
}